// Round 1
// baseline (3313.942 us; speedup 1.0000x reference)
//
#include <hip/hip_runtime.h>
#include <cmath>

// ---------------- utility ----------------
__global__ void fill_f32(float* __restrict__ p, float v, int n) {
    int i = blockIdx.x * blockDim.x + threadIdx.x;
    if (i < n) p[i] = v;
}

// ---------------- projection: xl = x@Wl, xr = x@Wr ----------------
// one block per node row; 256 threads: t<OUT -> xl col t, t in [128,128+OUT) -> xr col t-128
template<int K, int OUT>
__global__ void proj_kernel(const float* __restrict__ x,
                            const float* __restrict__ Wl,
                            const float* __restrict__ Wr,
                            float* __restrict__ xl,
                            float* __restrict__ xr,
                            int n)
{
    __shared__ float xs[K];
    int row = blockIdx.x;
    if (row >= n) return;
    int t = threadIdx.x;
    for (int k = t; k < K; k += 256) xs[k] = x[(size_t)row * K + k];
    __syncthreads();
    if (t < OUT) {
        float acc = 0.f;
        #pragma unroll 16
        for (int k = 0; k < K; ++k) acc += xs[k] * Wl[k * OUT + t];
        xl[(size_t)row * OUT + t] = acc;
    } else if (t >= 128 && (t - 128) < OUT) {
        int c = t - 128;
        float acc = 0.f;
        #pragma unroll 16
        for (int k = 0; k < K; ++k) acc += xs[k] * Wr[k * OUT + c];
        xr[(size_t)row * OUT + c] = acc;
    }
}

// ---------------- edge pass A: logits + segment max ----------------
__global__ void edge_logits_kernel(const float* __restrict__ xl,
                                   const float* __restrict__ xr,
                                   const int* __restrict__ src,
                                   const int* __restrict__ dst,
                                   const float* __restrict__ att,
                                   float* __restrict__ logits,
                                   float* __restrict__ lmax,
                                   int nE, int H, int C)
{
    int idx = blockIdx.x * blockDim.x + threadIdx.x;
    if (idx >= nE * H) return;
    int e = idx / H, h = idx - e * H;
    int s = src[e], d = dst[e];
    const float* pl = xl + (size_t)s * H * C + h * C;
    const float* pr = xr + (size_t)d * H * C + h * C;
    const float* pa = att + h * C;
    float acc = 0.f;
    for (int c = 0; c < C; ++c) {
        float v = pl[c] + pr[c];
        v = v > 0.f ? v : 0.2f * v;
        acc += v * pa[c];
    }
    logits[idx] = acc;
    float* addr = &lmax[(size_t)d * H + h];
    if (acc >= 0.f) atomicMax((int*)addr, __float_as_int(acc));
    else            atomicMin((unsigned int*)addr, __float_as_uint(acc));
}

// ---------------- edge pass B: p = exp(logit - lmax[dst]), denom += p ----------------
__global__ void edge_softmax_kernel(const int* __restrict__ dst,
                                    const float* __restrict__ lmax,
                                    float* __restrict__ p,     // in: logits, out: p
                                    float* __restrict__ denom,
                                    int nE, int H)
{
    int idx = blockIdx.x * blockDim.x + threadIdx.x;
    if (idx >= nE * H) return;
    int e = idx / H, h = idx - e * H;
    int d = dst[e];
    float v = expf(p[idx] - lmax[(size_t)d * H + h]);
    p[idx] = v;
    atomicAdd(&denom[(size_t)d * H + h], v);
}

// ---------------- edge pass C: acc[dst] += xl[src] * alpha ----------------
__global__ void edge_aggr_kernel(const int* __restrict__ src,
                                 const int* __restrict__ dst,
                                 const float* __restrict__ xl,
                                 const float* __restrict__ p,
                                 const float* __restrict__ denom,
                                 float* __restrict__ acc,
                                 int nE, int H, int C)
{
    int HC = H * C;
    long long idx = (long long)blockIdx.x * blockDim.x + threadIdx.x;
    if (idx >= (long long)nE * HC) return;
    int e = (int)(idx / HC);
    int i = (int)(idx - (long long)e * HC);
    int h = i / C;
    int s = src[e], d = dst[e];
    float alpha = p[(size_t)e * H + h] / fmaxf(denom[(size_t)d * H + h], 1e-16f);
    atomicAdd(&acc[(size_t)d * HC + i], xl[(size_t)s * HC + i] * alpha);
}

// ---------------- bias (+optional relu) ----------------
__global__ void bias_kernel(const float* __restrict__ acc, const float* __restrict__ b,
                            float* __restrict__ out, int n, int F, int do_relu)
{
    int idx = blockIdx.x * blockDim.x + threadIdx.x;
    if (idx >= n * F) return;
    float v = acc[idx] + b[idx % F];
    out[idx] = do_relu ? fmaxf(v, 0.f) : v;
}

extern "C" void kernel_launch(void* const* d_in, const int* in_sizes, int n_in,
                              void* d_out, int out_size, void* d_ws, size_t ws_size,
                              hipStream_t stream)
{
    const float* x    = (const float*)d_in[0];
    const int*   esrc = (const int*)d_in[1];
    const int*   edst = (const int*)d_in[2];
    const float* Wl0  = (const float*)d_in[3];
    const float* Wr0  = (const float*)d_in[4];
    const float* att0 = (const float*)d_in[5];
    const float* b0   = (const float*)d_in[6];
    const float* Wl1  = (const float*)d_in[7];
    const float* Wr1  = (const float*)d_in[8];
    const float* att1 = (const float*)d_in[9];
    const float* b1   = (const float*)d_in[10];
    const float* Wl2  = (const float*)d_in[11];
    const float* Wr2  = (const float*)d_in[12];
    const float* att2 = (const float*)d_in[13];
    const float* b2   = (const float*)d_in[14];
    float* out = (float*)d_out;

    const int N = in_sizes[0] / 128;   // 50000
    const int E = in_sizes[1];         // 850000

    char* ws = (char*)d_ws;
    size_t off = 0;
    auto walloc = [&](size_t bytes) -> void* {
        void* p = ws + off;
        off = (off + bytes + 255) & ~(size_t)255;
        return p;
    };
    float* xl    = (float*)walloc((size_t)N * 128 * 4);
    float* xr    = (float*)walloc((size_t)N * 128 * 4);
    float* hacc  = (float*)walloc((size_t)N * 128 * 4);
    float* pbuf  = (float*)walloc((size_t)E * 8 * 4);
    float* lmax  = (float*)walloc((size_t)N * 8 * 4);
    float* denom = (float*)walloc((size_t)N * 8 * 4);

    auto run_layer = [&](const float* xin, const float* Wl, const float* Wr,
                         const float* att, const float* b,
                         int H, int C, bool relu, float* final_out) {
        int HC = H * C;
        if (HC == 128) proj_kernel<128,128><<<N, 256, 0, stream>>>(xin, Wl, Wr, xl, xr, N);
        else           proj_kernel<128, 40><<<N, 256, 0, stream>>>(xin, Wl, Wr, xl, xr, N);
        int nh = N * H;
        fill_f32<<<(nh + 255) / 256, 256, 0, stream>>>(lmax, -INFINITY, nh);
        fill_f32<<<(nh + 255) / 256, 256, 0, stream>>>(denom, 0.f, nh);
        fill_f32<<<(N * HC + 255) / 256, 256, 0, stream>>>(hacc, 0.f, N * HC);
        int ne_h = E * H;
        edge_logits_kernel<<<(ne_h + 255) / 256, 256, 0, stream>>>(xl, xr, esrc, edst, att, pbuf, lmax, E, H, C);
        edge_softmax_kernel<<<(ne_h + 255) / 256, 256, 0, stream>>>(edst, lmax, pbuf, denom, E, H);
        long long tot = (long long)E * HC;
        int blocks = (int)((tot + 255) / 256);
        edge_aggr_kernel<<<blocks, 256, 0, stream>>>(esrc, edst, xl, pbuf, denom, hacc, E, H, C);
        bias_kernel<<<(N * HC + 255) / 256, 256, 0, stream>>>(hacc, b, final_out ? final_out : hacc, N, HC, relu ? 1 : 0);
    };

    run_layer(x,    Wl0, Wr0, att0, b0, 8, 16, true,  nullptr);
    run_layer(hacc, Wl1, Wr1, att1, b1, 8, 16, true,  nullptr);
    run_layer(hacc, Wl2, Wr2, att2, b2, 1, 40, false, out);
}